// Round 2
// baseline (609.195 us; speedup 1.0000x reference)
//
#include <hip/hip_runtime.h>

#define BEV_H 512
#define BEV_W 512
#define BEV_HW (BEV_H * BEV_W)
#define NB 8
#define NP 30000
#define NC 64

// Phase 2: record, per BEV cell, the highest pillar index p that maps to it.
// Matches the reference scatter "last write wins" semantics (highest p wins)
// — verified absmax 0.0 in R1.
__global__ void scatter_winner_kernel(const int* __restrict__ coords,
                                      int* __restrict__ winner) {
    int idx = blockIdx.x * blockDim.x + threadIdx.x;   // over NB*NP
    if (idx >= NB * NP) return;
    int b = idx / NP;
    int p = idx - b * NP;
    int2 c2 = ((const int2*)coords)[idx];              // coords[b][p][{x,y}]
    int gx = c2.x;
    int gy = c2.y;
    if (gx >= 0 && gx < BEV_W && gy >= 0 && gy < BEV_H) {
        atomicMax(&winner[b * BEV_HW + gy * BEV_W + gx], p);
    }
}

// Phase 3: cell-major gather. One thread per BEV cell, owning all 64 channels:
//  - winner read once (coalesced, 8 MB total)
//  - full 256 B feature row gathered as 16x float4 (every fetched byte used;
//    no reliance on cross-XCD L2 line reuse)
//  - 64 scalar stores: lanes = consecutive cells, so each channel's store is a
//    contiguous 256 B wave-coalesced segment at stride HW between channels.
// ~89% of cells are empty -> those threads only write zeros.
__global__ void gather_out_kernel(const float* __restrict__ feat,
                                  const int* __restrict__ winner,
                                  float* __restrict__ out) {
    int b = blockIdx.y;
    int cell = blockIdx.x * blockDim.x + threadIdx.x;  // 0..BEV_HW-1

    int w = winner[b * BEV_HW + cell];

    float4 r[16];
    if (w >= 0) {
        const float4* row = (const float4*)(feat + ((size_t)b * NP + w) * NC);
        #pragma unroll
        for (int j = 0; j < 16; ++j) r[j] = row[j];
    } else {
        #pragma unroll
        for (int j = 0; j < 16; ++j) r[j] = make_float4(0.f, 0.f, 0.f, 0.f);
    }

    float* o = out + (size_t)b * NC * BEV_HW + cell;
    #pragma unroll
    for (int j = 0; j < 16; ++j) {
        o[(size_t)(4 * j + 0) * BEV_HW] = r[j].x;
        o[(size_t)(4 * j + 1) * BEV_HW] = r[j].y;
        o[(size_t)(4 * j + 2) * BEV_HW] = r[j].z;
        o[(size_t)(4 * j + 3) * BEV_HW] = r[j].w;
    }
}

extern "C" void kernel_launch(void* const* d_in, const int* in_sizes, int n_in,
                              void* d_out, int out_size, void* d_ws, size_t ws_size,
                              hipStream_t stream) {
    const float* feat   = (const float*)d_in[0];   // (8, 30000, 64) f32
    const int*   coords = (const int*)d_in[1];     // (8, 30000, 2) i32
    float*       out    = (float*)d_out;           // (8, 64, 512, 512) f32
    int*         winner = (int*)d_ws;              // NB*BEV_HW ints = 8 MB

    // Phase 1: winner = -1 everywhere (0xFF bytes). Capturable memset node.
    hipMemsetAsync(winner, 0xFF, (size_t)NB * BEV_HW * sizeof(int), stream);

    // Phase 2: atomicMax scatter of pillar indices.
    {
        int total = NB * NP;
        int block = 256;
        int grid  = (total + block - 1) / block;
        scatter_winner_kernel<<<grid, block, 0, stream>>>(coords, winner);
    }

    // Phase 3: cell-major gather + coalesced write of full output.
    {
        dim3 block(256, 1, 1);
        dim3 grid(BEV_HW / 256, NB, 1);            // (1024, 8)
        gather_out_kernel<<<grid, block, 0, stream>>>(feat, winner, out);
    }
}

// Round 3
// 596.471 us; speedup vs baseline: 1.0213x; 1.0213x over previous
//
#include <hip/hip_runtime.h>

#define BEV_H 512
#define BEV_W 512
#define BEV_HW (BEV_H * BEV_W)
#define NB 8
#define NP 30000
#define NC 64

// Phase 2: record, per BEV cell, the highest pillar index p that maps to it.
// Matches reference "last write wins" (highest p) — absmax 0.0 since R1.
__global__ void scatter_winner_kernel(const int* __restrict__ coords,
                                      int* __restrict__ winner) {
    int idx = blockIdx.x * blockDim.x + threadIdx.x;   // over NB*NP
    if (idx >= NB * NP) return;
    int b = idx / NP;
    int p = idx - b * NP;
    int2 c2 = ((const int2*)coords)[idx];              // coords[b][p][{x,y}]
    int gx = c2.x;
    int gy = c2.y;
    if (gx >= 0 && gx < BEV_W && gy >= 0 && gy < BEV_H) {
        atomicMax(&winner[b * BEV_HW + gy * BEV_W + gx], p);
    }
}

// Phase 3: register-transpose gather. Block = 256 cells x 64 channels tile.
// Thread: 4 consecutive cells (cg = t&63) x 16 channels (cq = t>>6).
//  reads : int4 winner (coalesced); 4x float4 = 64 B per winning cell's row
//          (every fetched byte used; unique feat traffic only)
//  writes: 16x float4; lanes of a wave share cq and span 256 consecutive
//          cells -> each store instr = contiguous 1 KiB segment.
__global__ void __launch_bounds__(256)
gather_out_kernel(const float* __restrict__ feat,
                  const int* __restrict__ winner,
                  float* __restrict__ out) {
    int b  = blockIdx.y;
    int t  = threadIdx.x;
    int cg = t & 63;            // cell group of 4
    int cq = t >> 6;            // channel quarter (16 channels)
    int cell0 = blockIdx.x * 256 + 4 * cg;

    const int4 w4 = *(const int4*)(winner + b * BEV_HW + cell0);
    const int w[4] = {w4.x, w4.y, w4.z, w4.w};

    const float* fb = feat + (size_t)b * NP * NC + 16 * cq;

    float q[4][16];             // [cell][channel-within-quarter]
    #pragma unroll
    for (int j = 0; j < 4; ++j) {
        if (w[j] >= 0) {
            const float4* row = (const float4*)(fb + (size_t)w[j] * NC);
            *(float4*)&q[j][0]  = row[0];
            *(float4*)&q[j][4]  = row[1];
            *(float4*)&q[j][8]  = row[2];
            *(float4*)&q[j][12] = row[3];
        } else {
            #pragma unroll
            for (int i = 0; i < 16; ++i) q[j][i] = 0.0f;
        }
    }

    float* o = out + ((size_t)b * NC + 16 * cq) * BEV_HW + cell0;
    #pragma unroll
    for (int i = 0; i < 16; ++i) {
        float4 v = make_float4(q[0][i], q[1][i], q[2][i], q[3][i]);
        *(float4*)(o + (size_t)i * BEV_HW) = v;
    }
}

extern "C" void kernel_launch(void* const* d_in, const int* in_sizes, int n_in,
                              void* d_out, int out_size, void* d_ws, size_t ws_size,
                              hipStream_t stream) {
    const float* feat   = (const float*)d_in[0];   // (8, 30000, 64) f32
    const int*   coords = (const int*)d_in[1];     // (8, 30000, 2) i32
    float*       out    = (float*)d_out;           // (8, 64, 512, 512) f32
    int*         winner = (int*)d_ws;              // NB*BEV_HW ints = 8 MB

    // Phase 1: winner = -1 everywhere (0xFF bytes). Capturable memset node.
    hipMemsetAsync(winner, 0xFF, (size_t)NB * BEV_HW * sizeof(int), stream);

    // Phase 2: atomicMax scatter of pillar indices.
    {
        int total = NB * NP;
        int block = 256;
        int grid  = (total + block - 1) / block;
        scatter_winner_kernel<<<grid, block, 0, stream>>>(coords, winner);
    }

    // Phase 3: register-transpose gather, ideal reads + ideal writes.
    {
        dim3 block(256, 1, 1);
        dim3 grid(BEV_HW / 256, NB, 1);            // (1024, 8)
        gather_out_kernel<<<grid, block, 0, stream>>>(feat, winner, out);
    }
}